// Round 5
// baseline (184.262 us; speedup 1.0000x reference)
//
#include <hip/hip_runtime.h>
#include <math.h>

// Problem constants (reference: N=200000, D=256, 2 heads, 2 att iters)
#define NROWS 200000
#define D 256
#define F4 64          // float4 per row

// Grid: 1250 blocks x 160 rows = 200000 exactly.
// Block = 4 waves; wave = 4 x 16-lane row-groups; 10 iters x 4 rows.
#define NBLK 1250
#define CHUNK 160
#define ITERS 10

// Workspace layout (floats). No atomics -> no zeroing.
#define WS_H1 0          // 512   per-head h1
#define WS_H2 512        // 512   per-head h2
#define WS_A  1024       // 2*N   a1 per row (head0 then head1)
#define WS_P1 401024     // 1250*256 colsum partials
#define WS_P2 721024     // 1250*512 pass partials

__device__ __forceinline__ float att_sigmoid(float s) {
    float t = s / fmaxf(fabsf(s), 1e-12f);
    return 1.0f / (1.0f + __expf(-t));
}

__device__ __forceinline__ float dot4(float4 a, float4 b) {
    return fmaf(a.x, b.x, fmaf(a.y, b.y, fmaf(a.z, b.z, a.w * b.w)));
}

// reduce across the 16-lane row-group (xor 1,2,4,8)
__device__ __forceinline__ float group16_sum(float v) {
#pragma unroll
    for (int off = 1; off < 16; off <<= 1) v += __shfl_xor(v, off);
    return v;
}

// ---- colsum: per-block partial column sums (register double-buffered) ----
__global__ void __launch_bounds__(256) colsum_kernel(const float* __restrict__ x,
                                                     float* __restrict__ part) {
    const int tid = threadIdx.x, lane = tid & 63, wv = tid >> 6;
    const float4* x4 = reinterpret_cast<const float4*>(x);
    const size_t base = (size_t)(blockIdx.x * CHUNK + wv * 4) * F4 + lane;
    float4 cur[4], nxt[4];
#pragma unroll
    for (int j = 0; j < 4; ++j) cur[j] = x4[base + j * F4];
    float4 accA = make_float4(0.f, 0.f, 0.f, 0.f);
    float4 accB = make_float4(0.f, 0.f, 0.f, 0.f);
    for (int it = 0; it < ITERS; ++it) {
        if (it + 1 < ITERS) {
            size_t nb = base + (size_t)(it + 1) * 16 * F4;
#pragma unroll
            for (int j = 0; j < 4; ++j) nxt[j] = x4[nb + j * F4];
        }
        accA.x += cur[0].x + cur[1].x; accB.x += cur[2].x + cur[3].x;
        accA.y += cur[0].y + cur[1].y; accB.y += cur[2].y + cur[3].y;
        accA.z += cur[0].z + cur[1].z; accB.z += cur[2].z + cur[3].z;
        accA.w += cur[0].w + cur[1].w; accB.w += cur[2].w + cur[3].w;
        if (it + 1 < ITERS) {
#pragma unroll
            for (int j = 0; j < 4; ++j) cur[j] = nxt[j];
        }
    }
    accA.x += accB.x; accA.y += accB.y; accA.z += accB.z; accA.w += accB.w;
    __shared__ float4 sh[256];
    sh[tid] = accA;
    __syncthreads();
    if (tid < 64) {
        float4 a = sh[tid], b = sh[tid + 64], c = sh[tid + 128], d = sh[tid + 192];
        float4 s;
        s.x = (a.x + b.x) + (c.x + d.x);
        s.y = (a.y + b.y) + (c.y + d.y);
        s.z = (a.z + b.z) + (c.z + d.z);
        s.w = (a.w + b.w) + (c.w + d.w);
        reinterpret_cast<float4*>(part)[blockIdx.x * 64 + tid] = s;
    }
}

// ---- fused: reduce NBLK partial rows -> v, then h = tanh((v*scale) @ W) ----
__global__ void __launch_bounds__(256) hproj_fused(const float* __restrict__ W,
                                                   const float* __restrict__ part,
                                                   int width4, int headOff4, float scale,
                                                   float* __restrict__ hout) {
    const int head = blockIdx.x;
    const int tid = threadIdx.x, lane = tid & 63, wv = tid >> 6;
    const float4* p4 = reinterpret_cast<const float4*>(part) + head * headOff4 + lane;
    float4 s = make_float4(0.f, 0.f, 0.f, 0.f);
#pragma unroll 5
    for (int r = wv; r < NBLK; r += 4) {
        float4 v = p4[(size_t)r * width4];
        s.x += v.x; s.y += v.y; s.z += v.z; s.w += v.w;
    }
    __shared__ float4 red[4][64];
    __shared__ float vbuf[D];
    red[wv][lane] = s;
    __syncthreads();
    if (tid < 64) {
        float4 a = red[0][tid], b = red[1][tid], c = red[2][tid], d = red[3][tid];
        vbuf[tid * 4 + 0] = ((a.x + b.x) + (c.x + d.x)) * scale;
        vbuf[tid * 4 + 1] = ((a.y + b.y) + (c.y + d.y)) * scale;
        vbuf[tid * 4 + 2] = ((a.z + b.z) + (c.z + d.z)) * scale;
        vbuf[tid * 4 + 3] = ((a.w + b.w) + (c.w + d.w)) * scale;
    }
    __syncthreads();
    const float* Wh = W + head * D * D;
    float acc = 0.0f;
#pragma unroll 8
    for (int k = 0; k < D; ++k) acc = fmaf(vbuf[k], Wh[k * D + tid], acc);
    hout[head * D + tid] = tanhf(acc);
}

// ---- pass1: a1 = att_sigmoid(x.h1); partials of sum(a1*x); store a1 ----
// 16 lanes per row: lane (sub=lane>>4, li=lane&15); slice t covers f4 idx li+16t.
__global__ void __launch_bounds__(256) pass1_kernel(const float* __restrict__ x,
                                                    float* __restrict__ ws) {
    const float* h = ws + WS_H1;
    float* aA0 = ws + WS_A;
    float* aA1 = ws + WS_A + NROWS;
    float* part = ws + WS_P2;
    const int tid = threadIdx.x, lane = tid & 63, wv = tid >> 6;
    const int sub = lane >> 4, li = lane & 15;
    const float4* x4 = reinterpret_cast<const float4*>(x);
    const float4* h4 = reinterpret_cast<const float4*>(h);
    float4 h0v[4], h1v[4];
#pragma unroll
    for (int t = 0; t < 4; ++t) { h0v[t] = h4[li + 16 * t]; h1v[t] = h4[64 + li + 16 * t]; }
    const int row0 = blockIdx.x * CHUNK + wv * 4 + sub;
    const size_t base = (size_t)row0 * F4 + li;
    float4 cur[4], nxt[4];
#pragma unroll
    for (int t = 0; t < 4; ++t) cur[t] = x4[base + 16 * t];
    float4 acc0[4], acc1[4];
#pragma unroll
    for (int t = 0; t < 4; ++t) {
        acc0[t] = make_float4(0.f, 0.f, 0.f, 0.f);
        acc1[t] = make_float4(0.f, 0.f, 0.f, 0.f);
    }
    for (int it = 0; it < ITERS; ++it) {
        if (it + 1 < ITERS) {
            size_t nb = base + (size_t)(it + 1) * 16 * F4;
#pragma unroll
            for (int t = 0; t < 4; ++t) nxt[t] = x4[nb + 16 * t];
        }
        float d0 = (dot4(cur[0], h0v[0]) + dot4(cur[1], h0v[1]))
                 + (dot4(cur[2], h0v[2]) + dot4(cur[3], h0v[3]));
        float d1 = (dot4(cur[0], h1v[0]) + dot4(cur[1], h1v[1]))
                 + (dot4(cur[2], h1v[2]) + dot4(cur[3], h1v[3]));
        d0 = group16_sum(d0);
        d1 = group16_sum(d1);
        float a0 = att_sigmoid(d0);
        float a1 = att_sigmoid(d1);
        if (li == 0) {
            aA0[row0 + it * 16] = a0;
            aA1[row0 + it * 16] = a1;
        }
#pragma unroll
        for (int t = 0; t < 4; ++t) {
            acc0[t].x = fmaf(a0, cur[t].x, acc0[t].x);
            acc0[t].y = fmaf(a0, cur[t].y, acc0[t].y);
            acc0[t].z = fmaf(a0, cur[t].z, acc0[t].z);
            acc0[t].w = fmaf(a0, cur[t].w, acc0[t].w);
            acc1[t].x = fmaf(a1, cur[t].x, acc1[t].x);
            acc1[t].y = fmaf(a1, cur[t].y, acc1[t].y);
            acc1[t].z = fmaf(a1, cur[t].z, acc1[t].z);
            acc1[t].w = fmaf(a1, cur[t].w, acc1[t].w);
        }
        if (it + 1 < ITERS) {
#pragma unroll
            for (int t = 0; t < 4; ++t) cur[t] = nxt[t];
        }
    }
    __shared__ float4 sh[256][9];   // [tid][0..3]=head0 t, [4..7]=head1 t (pad to 9)
#pragma unroll
    for (int t = 0; t < 4; ++t) { sh[tid][t] = acc0[t]; sh[tid][4 + t] = acc1[t]; }
    __syncthreads();
    if (tid < 128) {
        const int hh = tid >> 6, f = tid & 63, fl = f & 15, ft = f >> 4;
        float4 s = make_float4(0.f, 0.f, 0.f, 0.f);
#pragma unroll
        for (int g = 0; g < 16; ++g) {
            float4 v = sh[(g >> 2) * 64 + (g & 3) * 16 + fl][hh * 4 + ft];
            s.x += v.x; s.y += v.y; s.z += v.z; s.w += v.w;
        }
        reinterpret_cast<float4*>(part)[blockIdx.x * 128 + tid] = s;
    }
}

// ---- pass2: a2 = att_sigmoid(a1*(x.h2)); partials of sum(a2*a1*x) ----
__global__ void __launch_bounds__(256) pass2_kernel(const float* __restrict__ x,
                                                    float* __restrict__ ws) {
    const float* h = ws + WS_H2;
    const float* aA0 = ws + WS_A;
    const float* aA1 = ws + WS_A + NROWS;
    float* part = ws + WS_P2;
    const int tid = threadIdx.x, lane = tid & 63, wv = tid >> 6;
    const int sub = lane >> 4, li = lane & 15;
    const float4* x4 = reinterpret_cast<const float4*>(x);
    const float4* h4 = reinterpret_cast<const float4*>(h);
    float4 h0v[4], h1v[4];
#pragma unroll
    for (int t = 0; t < 4; ++t) { h0v[t] = h4[li + 16 * t]; h1v[t] = h4[64 + li + 16 * t]; }
    const int row0 = blockIdx.x * CHUNK + wv * 4 + sub;
    const size_t base = (size_t)row0 * F4 + li;
    float4 cur[4], nxt[4];
    float caa0, caa1, naa0, naa1;
#pragma unroll
    for (int t = 0; t < 4; ++t) cur[t] = x4[base + 16 * t];
    caa0 = aA0[row0];
    caa1 = aA1[row0];
    float4 acc0[4], acc1[4];
#pragma unroll
    for (int t = 0; t < 4; ++t) {
        acc0[t] = make_float4(0.f, 0.f, 0.f, 0.f);
        acc1[t] = make_float4(0.f, 0.f, 0.f, 0.f);
    }
    for (int it = 0; it < ITERS; ++it) {
        if (it + 1 < ITERS) {
            size_t nb = base + (size_t)(it + 1) * 16 * F4;
#pragma unroll
            for (int t = 0; t < 4; ++t) nxt[t] = x4[nb + 16 * t];
            naa0 = aA0[row0 + (it + 1) * 16];
            naa1 = aA1[row0 + (it + 1) * 16];
        }
        float d0 = (dot4(cur[0], h0v[0]) + dot4(cur[1], h0v[1]))
                 + (dot4(cur[2], h0v[2]) + dot4(cur[3], h0v[3]));
        float d1 = (dot4(cur[0], h1v[0]) + dot4(cur[1], h1v[1]))
                 + (dot4(cur[2], h1v[2]) + dot4(cur[3], h1v[3]));
        d0 = group16_sum(d0);
        d1 = group16_sum(d1);
        float w0 = att_sigmoid(caa0 * d0) * caa0;
        float w1 = att_sigmoid(caa1 * d1) * caa1;
#pragma unroll
        for (int t = 0; t < 4; ++t) {
            acc0[t].x = fmaf(w0, cur[t].x, acc0[t].x);
            acc0[t].y = fmaf(w0, cur[t].y, acc0[t].y);
            acc0[t].z = fmaf(w0, cur[t].z, acc0[t].z);
            acc0[t].w = fmaf(w0, cur[t].w, acc0[t].w);
            acc1[t].x = fmaf(w1, cur[t].x, acc1[t].x);
            acc1[t].y = fmaf(w1, cur[t].y, acc1[t].y);
            acc1[t].z = fmaf(w1, cur[t].z, acc1[t].z);
            acc1[t].w = fmaf(w1, cur[t].w, acc1[t].w);
        }
        if (it + 1 < ITERS) {
#pragma unroll
            for (int t = 0; t < 4; ++t) cur[t] = nxt[t];
            caa0 = naa0; caa1 = naa1;
        }
    }
    __shared__ float4 sh[256][9];
#pragma unroll
    for (int t = 0; t < 4; ++t) { sh[tid][t] = acc0[t]; sh[tid][4 + t] = acc1[t]; }
    __syncthreads();
    if (tid < 128) {
        const int hh = tid >> 6, f = tid & 63, fl = f & 15, ft = f >> 4;
        float4 s = make_float4(0.f, 0.f, 0.f, 0.f);
#pragma unroll
        for (int g = 0; g < 16; ++g) {
            float4 v = sh[(g >> 2) * 64 + (g & 3) * 16 + fl][hh * 4 + ft];
            s.x += v.x; s.y += v.y; s.z += v.z; s.w += v.w;
        }
        reinterpret_cast<float4*>(part)[blockIdx.x * 128 + tid] = s;
    }
}

// ---- final: out[head*256+c] = sum over NBLK partial rows (direct store) ----
__global__ void __launch_bounds__(256) out_reduce(const float* __restrict__ part,
                                                  float* __restrict__ out) {
    const int head = blockIdx.x;
    const int tid = threadIdx.x, lane = tid & 63, wv = tid >> 6;
    const float4* p4 = reinterpret_cast<const float4*>(part) + head * 64 + lane;
    float4 s = make_float4(0.f, 0.f, 0.f, 0.f);
#pragma unroll 5
    for (int r = wv; r < NBLK; r += 4) {
        float4 v = p4[(size_t)r * 128];
        s.x += v.x; s.y += v.y; s.z += v.z; s.w += v.w;
    }
    __shared__ float4 red[4][64];
    red[wv][lane] = s;
    __syncthreads();
    if (tid < 64) {
        float4 a = red[0][tid], b = red[1][tid], c = red[2][tid], d = red[3][tid];
        float4 o;
        o.x = (a.x + b.x) + (c.x + d.x);
        o.y = (a.y + b.y) + (c.y + d.y);
        o.z = (a.z + b.z) + (c.z + d.z);
        o.w = (a.w + b.w) + (c.w + d.w);
        reinterpret_cast<float4*>(out)[head * 64 + tid] = o;
    }
}

extern "C" void kernel_launch(void* const* d_in, const int* in_sizes, int n_in,
                              void* d_out, int out_size, void* d_ws, size_t ws_size,
                              hipStream_t stream) {
    const float* x = (const float*)d_in[0];   // (200000, 256) f32
    const float* W = (const float*)d_in[1];   // (2, 256, 256) f32
    float* out = (float*)d_out;               // (1, 512) f32
    float* ws = (float*)d_ws;

    colsum_kernel<<<dim3(NBLK), dim3(256), 0, stream>>>(x, ws + WS_P1);
    hproj_fused<<<dim3(2), dim3(256), 0, stream>>>(W, ws + WS_P1, 64, 0, 1.0f / NROWS, ws + WS_H1);
    pass1_kernel<<<dim3(NBLK), dim3(256), 0, stream>>>(x, ws);
    hproj_fused<<<dim3(2), dim3(256), 0, stream>>>(W, ws + WS_P2, 128, 64, 1.0f / NROWS, ws + WS_H2);
    pass2_kernel<<<dim3(NBLK), dim3(256), 0, stream>>>(x, ws);
    out_reduce<<<dim3(2), dim3(256), 0, stream>>>(ws + WS_P2, out);
}